// Round 3
// baseline (896.177 us; speedup 1.0000x reference)
//
#include <hip/hip_runtime.h>
#include <math.h>

// Problem constants: B=512, C=50000, D=256.
#define D_DIM 256
#define TM 128
#define TN 128
#define LSTR 40   // LDS row stride in bf16 elems (80 B, breaks bank pattern)

typedef __attribute__((ext_vector_type(8))) short short8;
typedef __attribute__((ext_vector_type(4))) float floatx4;

__device__ __forceinline__ unsigned short f2bf(float f) {
    unsigned int u = __float_as_uint(f);
    u += 0x7FFFu + ((u >> 16) & 1u);   // round-to-nearest-even
    return (unsigned short)(u >> 16);
}

__device__ __forceinline__ short8 pack8(float4 x, float4 y, float s) {
    short8 r;
    r[0] = (short)f2bf(x.x * s); r[1] = (short)f2bf(x.y * s);
    r[2] = (short)f2bf(x.z * s); r[3] = (short)f2bf(x.w * s);
    r[4] = (short)f2bf(y.x * s); r[5] = (short)f2bf(y.y * s);
    r[6] = (short)f2bf(y.z * s); r[7] = (short)f2bf(y.w * s);
    return r;
}

// ---------------- init: zero accumulators + loaded mask ----------------
__global__ void init_zero(float* ws, int nwords) {
    int i = blockIdx.x * blockDim.x + threadIdx.x;
    if (i < nwords) ws[i] = 0.0f;
}

// ---------------- row norms (one wave per row) + scatter loaded mask ----------------
__global__ void norms_scatter(const float* __restrict__ V, const float* __restrict__ T,
                              const int* __restrict__ ids, unsigned char* loaded,
                              float* __restrict__ inv_v, float* __restrict__ inv_t,
                              int B, int C, int n_loaded) {
    int gtid = blockIdx.x * blockDim.x + threadIdx.x;
    if (gtid < n_loaded) loaded[ids[gtid]] = 1;

    int wave = gtid >> 6;
    int lane = threadIdx.x & 63;
    if (wave >= B + C) return;  // whole wave uniform
    const float* src = (wave < B) ? (V + (size_t)wave * D_DIM)
                                  : (T + (size_t)(wave - B) * D_DIM);
    float4 x = ((const float4*)src)[lane];
    float ss = x.x * x.x + x.y * x.y + x.z * x.z + x.w * x.w;
    #pragma unroll
    for (int off = 32; off > 0; off >>= 1) ss += __shfl_xor(ss, off);
    if (lane == 0) {
        float nrm = sqrtf(ss);
        if (wave < B) inv_v[wave] = 1.0f / nrm;                 // visual: no eps
        else          inv_t[wave - B] = 1.0f / (1e-6f + nrm);   // text: +1e-6 on norm
    }
}

// ---------------- compress labels -> per-row 64-bit posmask words ----------------
// One thread per label (coalesced 102 MB stream). Wave = 64 consecutive cols of
// one row -> one ballot word. Also emits loadedmask (row 0) and n_pos[row].
__global__ void compress_labels(const int* __restrict__ label,
                                const unsigned char* __restrict__ loaded,
                                unsigned long long* __restrict__ posmask,
                                unsigned long long* __restrict__ loadedmask,
                                float* __restrict__ nposf,
                                int B, int C, int WPR) {
    long long gtid = (long long)blockIdx.x * blockDim.x + threadIdx.x;
    int waveId = (int)(gtid >> 6);
    int lane = threadIdx.x & 63;
    if (waveId >= B * WPR) return;
    int row  = waveId / WPR;
    int wcol = waveId - row * WPR;
    int col  = (wcol << 6) | lane;
    int inb  = col < C;
    int lab  = inb ? label[(size_t)row * C + col] : 0;
    int ld   = inb ? (int)loaded[col] : 0;
    unsigned long long posw = __ballot(lab && ld);
    unsigned long long ldw  = __ballot(ld != 0);
    if (lane == 0) {
        posmask[(size_t)row * WPR + wcol] = posw;
        if (row == 0) loadedmask[wcol] = ldw;
        float np = (float)__popcll(posw);
        if (np != 0.f) atomicAdd(&nposf[row], np);
    }
}

// ---------------- bf16 MFMA GEMM (S = Vn * Tn^T) + fused masked epilogue ----------------
__global__ __launch_bounds__(256) void gemm_mfma(
    const float* __restrict__ V, const float* __restrict__ T,
    const unsigned long long* __restrict__ posmask,
    const unsigned long long* __restrict__ loadedmask,
    const float* __restrict__ inv_v, const float* __restrict__ inv_t,
    float* __restrict__ denom, float* __restrict__ pos_sum,
    int C, int WPR) {
    __shared__ unsigned short As[TM * LSTR];   // [row][k] bf16, stride 40
    __shared__ unsigned short Bs[TN * LSTR];
    __shared__ float sDen[TM], sPos[TM];

    const int tid  = threadIdx.x;
    const int lane = tid & 63;
    const int w    = tid >> 6;
    const int m0 = blockIdx.y * TM;
    const int n0 = blockIdx.x * TN;

    if (tid < TM) { sDen[tid] = 0.f; sPos[tid] = 0.f; }

    // ---- staging: wave w stages tile rows [w*32, w*32+32) of A and B
    const int sr = lane >> 2;          // 0..15 row within issue
    const int kq = lane & 3;           // k-chunk 0..3 (8 floats each)
    const int kb = kq * 8;
    const int ra0 = w * 32 + sr;       // issue-0 tile row; issue-1 = +16
    const int gm0 = m0 + ra0, gm1 = gm0 + 16;
    const float sa0 = inv_v[gm0], sa1 = inv_v[gm1];
    int gc0 = n0 + ra0, gc1 = gc0 + 16;
    const float sb0 = (gc0 < C) ? inv_t[gc0] : 0.f;
    const float sb1 = (gc1 < C) ? inv_t[gc1] : 0.f;
    if (gc0 >= C) gc0 = 0;
    if (gc1 >= C) gc1 = 0;
    const float* pa0 = V + (size_t)gm0 * D_DIM + kb;
    const float* pa1 = V + (size_t)gm1 * D_DIM + kb;
    const float* pb0 = T + (size_t)gc0 * D_DIM + kb;
    const float* pb1 = T + (size_t)gc1 * D_DIM + kb;
    unsigned short* wa0 = &As[ra0 * LSTR + kb];
    unsigned short* wa1 = &As[(ra0 + 16) * LSTR + kb];
    unsigned short* wb0 = &Bs[ra0 * LSTR + kb];
    unsigned short* wb1 = &Bs[(ra0 + 16) * LSTR + kb];

    // ---- compute-side: 2x2 waves, each 64x64 via 4x4 fragments of 16x16x32
    const int wm = (w >> 1) * 64;
    const int wn = (w & 1) * 64;
    const int fr = lane & 15;
    const int quad = lane >> 4;

    floatx4 acc[4][4];
    #pragma unroll
    for (int mi = 0; mi < 4; mi++)
        #pragma unroll
        for (int ni = 0; ni < 4; ni++) acc[mi][ni] = (floatx4)0.f;

    float4 a00 = *(const float4*)(pa0 + 0), a01 = *(const float4*)(pa0 + 4);
    float4 a10 = *(const float4*)(pa1 + 0), a11 = *(const float4*)(pa1 + 4);
    float4 b00 = *(const float4*)(pb0 + 0), b01 = *(const float4*)(pb0 + 4);
    float4 b10 = *(const float4*)(pb1 + 0), b11 = *(const float4*)(pb1 + 4);

    #pragma unroll
    for (int kt = 0; kt < D_DIM / 32; ++kt) {
        if (kt) __syncthreads();  // protect previous iter's frag reads
        *(short8*)wa0 = pack8(a00, a01, sa0);
        *(short8*)wa1 = pack8(a10, a11, sa1);
        *(short8*)wb0 = pack8(b00, b01, sb0);
        *(short8*)wb1 = pack8(b10, b11, sb1);
        if (kt + 1 < D_DIM / 32) {
            int ko = (kt + 1) * 32;
            a00 = *(const float4*)(pa0 + ko); a01 = *(const float4*)(pa0 + ko + 4);
            a10 = *(const float4*)(pa1 + ko); a11 = *(const float4*)(pa1 + ko + 4);
            b00 = *(const float4*)(pb0 + ko); b01 = *(const float4*)(pb0 + ko + 4);
            b10 = *(const float4*)(pb1 + ko); b11 = *(const float4*)(pb1 + ko + 4);
        }
        __syncthreads();
        short8 af[4], bf[4];
        #pragma unroll
        for (int mi = 0; mi < 4; mi++)
            af[mi] = *(const short8*)&As[(wm + mi * 16 + fr) * LSTR + quad * 8];
        #pragma unroll
        for (int ni = 0; ni < 4; ni++)
            bf[ni] = *(const short8*)&Bs[(wn + ni * 16 + fr) * LSTR + quad * 8];
        #pragma unroll
        for (int mi = 0; mi < 4; mi++)
            #pragma unroll
            for (int ni = 0; ni < 4; ni++)
                acc[mi][ni] = __builtin_amdgcn_mfma_f32_16x16x32_bf16(
                    af[mi], bf[ni], acc[mi][ni], 0, 0, 0);
    }

    // ---- epilogue: mask-word based per-row reduction.
    // D layout: row = quad*4 + reg, col = lane&15 (within each 16x16 fragment).
    // cols covered by this wave: [n0+wn, n0+wn+64) == one 64-bit mask word.
    const int wcol = (n0 + wn) >> 6;
    const unsigned long long loadedw = loadedmask[wcol];
    #pragma unroll
    for (int mi = 0; mi < 4; mi++) {
        #pragma unroll
        for (int i = 0; i < 4; i++) {
            const int mloc = wm + mi * 16 + quad * 4 + i;
            const int gr = m0 + mloc;
            const unsigned long long posw = posmask[(size_t)gr * WPR + wcol];
            const unsigned long long negw = loadedw & ~posw;
            float den = 0.f, pos = 0.f;
            #pragma unroll
            for (int ni = 0; ni < 4; ni++) {
                const float s = acc[mi][ni][i];
                const int b = ni * 16 + fr;
                if ((negw >> b) & 1) den += __expf(s);
                if ((posw >> b) & 1) pos += s;
            }
            // reduce across the 16 lanes of this quad (same output row)
            #pragma unroll
            for (int off = 8; off >= 1; off >>= 1) {
                den += __shfl_xor(den, off);
                pos += __shfl_xor(pos, off);
            }
            if (fr == 0) {
                if (den != 0.f) atomicAdd(&sDen[mloc], den);
                if (pos != 0.f) atomicAdd(&sPos[mloc], pos);
            }
        }
    }
    __syncthreads();
    if (tid < TM) {
        int gr = m0 + tid;
        if (sDen[tid] != 0.f) atomicAdd(&denom[gr], sDen[tid]);
        if (sPos[tid] != 0.f) atomicAdd(&pos_sum[gr], sPos[tid]);
    }
}

// ---------------- finalize ----------------
__global__ void finalize(const float* __restrict__ denom, const float* __restrict__ pos_sum,
                         const float* __restrict__ nposf, float* __restrict__ out, int B) {
    __shared__ float red[512];
    int tid = threadIdx.x;
    float pr = 0.f;
    if (tid < B) pr = logf(denom[tid]) - pos_sum[tid] / nposf[tid];
    red[tid] = pr;
    __syncthreads();
    for (int s = 256; s > 0; s >>= 1) {
        if (tid < s) red[tid] += red[tid + s];
        __syncthreads();
    }
    if (tid == 0) out[0] = red[0] / (float)B;
}

extern "C" void kernel_launch(void* const* d_in, const int* in_sizes, int n_in,
                              void* d_out, int out_size, void* d_ws, size_t ws_size,
                              hipStream_t stream) {
    const float* V     = (const float*)d_in[0];
    const float* T     = (const float*)d_in[1];
    const int*   label = (const int*)d_in[2];
    const int*   ids   = (const int*)d_in[3];
    int B = in_sizes[0] / D_DIM;   // 512
    int C = in_sizes[1] / D_DIM;   // 50000
    int n_loaded = in_sizes[3];    // 40000
    int WPR = (C + 63) >> 6;       // mask words per row (782)

    // ws layout (bytes):
    //   0      : denom   [512 f]
    //   2048   : pos_sum [512 f]
    //   4096   : nposf   [512 f]
    //   6144   : loaded mask [C bytes, padded to 50176]
    //   56320  : inv_v [512 f]
    //   58368  : inv_t [C f]                (ends 258368)
    //   258368 : loadedmask [WPR u64]       (6256 B, ends 264624)
    //   264624 : posmask [B*WPR u64]        (3.2 MB, ends ~3.47 MB)
    char* ws = (char*)d_ws;
    float* denom   = (float*)(ws + 0);
    float* pos_sum = (float*)(ws + 2048);
    float* nposf   = (float*)(ws + 4096);
    unsigned char* loaded = (unsigned char*)(ws + 6144);
    float* inv_v   = (float*)(ws + 56320);
    float* inv_t   = (float*)(ws + 58368);
    unsigned long long* loadedmask = (unsigned long long*)(ws + 258368);
    unsigned long long* posmask    = (unsigned long long*)(ws + 264624);

    int zero_words = (6144 + 50176) / 4;  // accumulators + loaded byte mask
    init_zero<<<(zero_words + 255) / 256, 256, 0, stream>>>((float*)ws, zero_words);

    int waves = B + C;
    int threads_needed = waves * 64;
    norms_scatter<<<(threads_needed + 255) / 256, 256, 0, stream>>>(
        V, T, ids, loaded, inv_v, inv_t, B, C, n_loaded);

    long long cthreads = (long long)B * WPR * 64;
    compress_labels<<<(int)((cthreads + 255) / 256), 256, 0, stream>>>(
        label, loaded, posmask, loadedmask, nposf, B, C, WPR);

    dim3 grid((C + TN - 1) / TN, B / TM);
    gemm_mfma<<<grid, 256, 0, stream>>>(V, T, posmask, loadedmask, inv_v, inv_t,
                                        denom, pos_sum, C, WPR);

    finalize<<<1, 512, 0, stream>>>(denom, pos_sum, nposf, (float*)d_out, B);
}

// Round 4
// 412.995 us; speedup vs baseline: 2.1699x; 2.1699x over previous
//
#include <hip/hip_runtime.h>
#include <math.h>

// Problem constants: B=512, C=50000, D=256.
#define D_DIM 256
#define TM 128
#define TN 128
#define LSTR 40   // LDS row stride in bf16 elems (80 B, breaks bank pattern)

typedef __attribute__((ext_vector_type(8))) short short8;
typedef __attribute__((ext_vector_type(4))) float floatx4;
typedef unsigned long long u64;

__device__ __forceinline__ unsigned short f2bf(float f) {
    unsigned int u = __float_as_uint(f);
    u += 0x7FFFu + ((u >> 16) & 1u);   // round-to-nearest-even
    return (unsigned short)(u >> 16);
}

__device__ __forceinline__ short8 pack8(float4 x, float4 y, float s) {
    short8 r;
    r[0] = (short)f2bf(x.x * s); r[1] = (short)f2bf(x.y * s);
    r[2] = (short)f2bf(x.z * s); r[3] = (short)f2bf(x.w * s);
    r[4] = (short)f2bf(y.x * s); r[5] = (short)f2bf(y.y * s);
    r[6] = (short)f2bf(y.z * s); r[7] = (short)f2bf(y.w * s);
    return r;
}

// ---------------- init: zero loadedmask only ----------------
__global__ void init_zero(u64* lm, int nwords) {
    int i = blockIdx.x * blockDim.x + threadIdx.x;
    if (i < nwords) lm[i] = 0ull;
}

// ---------------- row norms (one wave per row) + build loadedmask via int atomicOr ----
__global__ void norms_scatter(const float* __restrict__ V, const float* __restrict__ T,
                              const int* __restrict__ ids, u64* __restrict__ loadedmask,
                              float* __restrict__ inv_v, float* __restrict__ inv_t,
                              int B, int C, int n_loaded) {
    int gtid = blockIdx.x * blockDim.x + threadIdx.x;
    if (gtid < n_loaded) {
        int id = ids[gtid];
        atomicOr(&loadedmask[id >> 6], 1ull << (id & 63));   // native int64 atomic
    }

    int wave = gtid >> 6;
    int lane = threadIdx.x & 63;
    if (wave >= B + C) return;  // whole wave uniform
    const float* src = (wave < B) ? (V + (size_t)wave * D_DIM)
                                  : (T + (size_t)(wave - B) * D_DIM);
    float4 x = ((const float4*)src)[lane];
    float ss = x.x * x.x + x.y * x.y + x.z * x.z + x.w * x.w;
    #pragma unroll
    for (int off = 32; off > 0; off >>= 1) ss += __shfl_xor(ss, off);
    if (lane == 0) {
        float nrm = sqrtf(ss);
        if (wave < B) inv_v[wave] = 1.0f / nrm;                 // visual: no eps
        else          inv_t[wave - B] = 1.0f / (1e-6f + nrm);   // text: +1e-6 on norm
    }
}

// ---------------- compress labels -> per-row 64-bit posmask words (NO atomics) -------
// grid = (ceil(WPR/4), B). One wave per 64 consecutive cols of one row.
__global__ void compress_labels(const int* __restrict__ label,
                                const u64* __restrict__ loadedmask,
                                u64* __restrict__ posmask,
                                int C, int WPR) {
    int row  = blockIdx.y;
    int wcol = blockIdx.x * 4 + (threadIdx.x >> 6);
    int lane = threadIdx.x & 63;
    if (wcol >= WPR) return;
    u64 ldw = loadedmask[wcol];                 // wave-uniform scalar load
    int col = (wcol << 6) | lane;
    int lab = (col < C) ? label[(size_t)row * C + col] : 0;
    u64 posw = __ballot(lab && ((ldw >> lane) & 1));
    if (lane == 0) posmask[(size_t)row * WPR + wcol] = posw;
}

// ---------------- n_pos[row] = popcount of posmask row (one wave per row) ------------
__global__ void count_pos(const u64* __restrict__ posmask, float* __restrict__ nposf,
                          int B, int WPR) {
    int row  = blockIdx.x * 4 + (threadIdx.x >> 6);
    int lane = threadIdx.x & 63;
    if (row >= B) return;
    int cnt = 0;
    for (int j = lane; j < WPR; j += 64)
        cnt += __popcll(posmask[(size_t)row * WPR + j]);
    #pragma unroll
    for (int off = 32; off > 0; off >>= 1) cnt += __shfl_xor(cnt, off);
    if (lane == 0) nposf[row] = (float)cnt;
}

// ---------------- bf16 MFMA GEMM (S = Vn * Tn^T) + fused masked epilogue -------------
// Writes per-block partials (no global atomics).
__global__ __launch_bounds__(256) void gemm_mfma(
    const float* __restrict__ V, const float* __restrict__ T,
    const u64* __restrict__ posmask, const u64* __restrict__ loadedmask,
    const float* __restrict__ inv_v, const float* __restrict__ inv_t,
    float* __restrict__ denomP, float* __restrict__ posP,
    int C, int WPR) {
    __shared__ unsigned short As[TM * LSTR];   // [row][k] bf16, stride 40
    __shared__ unsigned short Bs[TN * LSTR];
    __shared__ float sDen[TM], sPos[TM];

    const int tid  = threadIdx.x;
    const int lane = tid & 63;
    const int w    = tid >> 6;
    const int m0 = blockIdx.y * TM;
    const int n0 = blockIdx.x * TN;

    if (tid < TM) { sDen[tid] = 0.f; sPos[tid] = 0.f; }

    // ---- staging: wave w stages tile rows [w*32, w*32+32) of A and B
    const int sr = lane >> 2;          // 0..15 row within issue
    const int kq = lane & 3;           // k-chunk 0..3 (8 floats each)
    const int kb = kq * 8;
    const int ra0 = w * 32 + sr;       // issue-0 tile row; issue-1 = +16
    const int gm0 = m0 + ra0, gm1 = gm0 + 16;
    const float sa0 = inv_v[gm0], sa1 = inv_v[gm1];
    int gc0 = n0 + ra0, gc1 = gc0 + 16;
    const float sb0 = (gc0 < C) ? inv_t[gc0] : 0.f;
    const float sb1 = (gc1 < C) ? inv_t[gc1] : 0.f;
    if (gc0 >= C) gc0 = 0;
    if (gc1 >= C) gc1 = 0;
    const float* pa0 = V + (size_t)gm0 * D_DIM + kb;
    const float* pa1 = V + (size_t)gm1 * D_DIM + kb;
    const float* pb0 = T + (size_t)gc0 * D_DIM + kb;
    const float* pb1 = T + (size_t)gc1 * D_DIM + kb;
    unsigned short* wa0 = &As[ra0 * LSTR + kb];
    unsigned short* wa1 = &As[(ra0 + 16) * LSTR + kb];
    unsigned short* wb0 = &Bs[ra0 * LSTR + kb];
    unsigned short* wb1 = &Bs[(ra0 + 16) * LSTR + kb];

    // ---- compute-side: 2x2 waves, each 64x64 via 4x4 fragments of 16x16x32
    const int wm = (w >> 1) * 64;
    const int wn = (w & 1) * 64;
    const int fr = lane & 15;
    const int quad = lane >> 4;

    floatx4 acc[4][4];
    #pragma unroll
    for (int mi = 0; mi < 4; mi++)
        #pragma unroll
        for (int ni = 0; ni < 4; ni++) acc[mi][ni] = (floatx4)0.f;

    float4 a00 = *(const float4*)(pa0 + 0), a01 = *(const float4*)(pa0 + 4);
    float4 a10 = *(const float4*)(pa1 + 0), a11 = *(const float4*)(pa1 + 4);
    float4 b00 = *(const float4*)(pb0 + 0), b01 = *(const float4*)(pb0 + 4);
    float4 b10 = *(const float4*)(pb1 + 0), b11 = *(const float4*)(pb1 + 4);

    #pragma unroll
    for (int kt = 0; kt < D_DIM / 32; ++kt) {
        if (kt) __syncthreads();  // protect previous iter's frag reads
        *(short8*)wa0 = pack8(a00, a01, sa0);
        *(short8*)wa1 = pack8(a10, a11, sa1);
        *(short8*)wb0 = pack8(b00, b01, sb0);
        *(short8*)wb1 = pack8(b10, b11, sb1);
        if (kt + 1 < D_DIM / 32) {
            int ko = (kt + 1) * 32;
            a00 = *(const float4*)(pa0 + ko); a01 = *(const float4*)(pa0 + ko + 4);
            a10 = *(const float4*)(pa1 + ko); a11 = *(const float4*)(pa1 + ko + 4);
            b00 = *(const float4*)(pb0 + ko); b01 = *(const float4*)(pb0 + ko + 4);
            b10 = *(const float4*)(pb1 + ko); b11 = *(const float4*)(pb1 + ko + 4);
        }
        __syncthreads();
        short8 af[4], bf[4];
        #pragma unroll
        for (int mi = 0; mi < 4; mi++)
            af[mi] = *(const short8*)&As[(wm + mi * 16 + fr) * LSTR + quad * 8];
        #pragma unroll
        for (int ni = 0; ni < 4; ni++)
            bf[ni] = *(const short8*)&Bs[(wn + ni * 16 + fr) * LSTR + quad * 8];
        #pragma unroll
        for (int mi = 0; mi < 4; mi++)
            #pragma unroll
            for (int ni = 0; ni < 4; ni++)
                acc[mi][ni] = __builtin_amdgcn_mfma_f32_16x16x32_bf16(
                    af[mi], bf[ni], acc[mi][ni], 0, 0, 0);
    }

    // ---- epilogue: mask-word based per-row reduction.
    // D layout: row = quad*4 + reg, col = lane&15 (within each 16x16 fragment).
    const int wcol = (n0 + wn) >> 6;
    const u64 loadedw = loadedmask[wcol];
    #pragma unroll
    for (int mi = 0; mi < 4; mi++) {
        #pragma unroll
        for (int i = 0; i < 4; i++) {
            const int mloc = wm + mi * 16 + quad * 4 + i;
            const int gr = m0 + mloc;
            const u64 posw = posmask[(size_t)gr * WPR + wcol];
            const u64 negw = loadedw & ~posw;
            float den = 0.f, pos = 0.f;
            #pragma unroll
            for (int ni = 0; ni < 4; ni++) {
                const float s = acc[mi][ni][i];
                const int b = ni * 16 + fr;
                if ((negw >> b) & 1) den += __expf(s);
                if ((posw >> b) & 1) pos += s;
            }
            // reduce across the 16 lanes of this quad (same output row)
            #pragma unroll
            for (int off = 8; off >= 1; off >>= 1) {
                den += __shfl_xor(den, off);
                pos += __shfl_xor(pos, off);
            }
            if (fr == 0) {   // LDS atomics only (fast, block-local)
                if (den != 0.f) atomicAdd(&sDen[mloc], den);
                if (pos != 0.f) atomicAdd(&sPos[mloc], pos);
            }
        }
    }
    __syncthreads();
    if (tid < TM) {
        // partial index: [bn][global row], coalesced 128-float store
        size_t idx = (size_t)blockIdx.x * (gridDim.y * TM) + m0 + tid;
        denomP[idx] = sDen[tid];
        posP[idx]   = sPos[tid];
    }
}

// ---------------- finalize: sum partials, per_row = log(den) - pos/np; mean ----------
__global__ void finalize(const float* __restrict__ denomP, const float* __restrict__ posP,
                         const float* __restrict__ nposf, float* __restrict__ out,
                         int B, int NB) {
    __shared__ float red[512];
    int tid = threadIdx.x;
    float pr = 0.f;
    if (tid < B) {
        float den = 0.f, pos = 0.f;
        for (int bn = 0; bn < NB; bn++) {
            den += denomP[(size_t)bn * B + tid];   // coalesced across threads
            pos += posP[(size_t)bn * B + tid];
        }
        pr = logf(den) - pos / nposf[tid];
    }
    red[tid] = pr;
    __syncthreads();
    for (int s = 256; s > 0; s >>= 1) {
        if (tid < s) red[tid] += red[tid + s];
        __syncthreads();
    }
    if (tid == 0) out[0] = red[0] / (float)B;
}

extern "C" void kernel_launch(void* const* d_in, const int* in_sizes, int n_in,
                              void* d_out, int out_size, void* d_ws, size_t ws_size,
                              hipStream_t stream) {
    const float* V     = (const float*)d_in[0];
    const float* T     = (const float*)d_in[1];
    const int*   label = (const int*)d_in[2];
    const int*   ids   = (const int*)d_in[3];
    int B = in_sizes[0] / D_DIM;   // 512
    int C = in_sizes[1] / D_DIM;   // 50000
    int n_loaded = in_sizes[3];    // 40000
    int WPR = (C + 63) >> 6;       // mask words per row (782)
    int NB  = (C + TN - 1) / TN;   // n-blocks (391)

    // ws layout (bytes):
    //   0        : nposf [512 f]
    //   2048     : inv_v [512 f]
    //   4096     : inv_t [C f]               (ends 204096)
    //   204096   : loadedmask [WPR u64]      (6256 B, ends 210352; 8-aligned)
    //   210432   : posmask [B*WPR u64]       (3.20 MB, ends 3413504)
    //   3413504  : denomP [NB*B f]           (800768 B, ends 4214272)
    //   4214272  : posP   [NB*B f]           (800768 B, ends 5015040)
    char* ws = (char*)d_ws;
    float* nposf   = (float*)(ws + 0);
    float* inv_v   = (float*)(ws + 2048);
    float* inv_t   = (float*)(ws + 4096);
    u64*   loadedmask = (u64*)(ws + 204096);
    u64*   posmask    = (u64*)(ws + 210432);
    float* denomP  = (float*)(ws + 3413504);
    float* posP    = (float*)(ws + 4214272);

    init_zero<<<(WPR + 255) / 256, 256, 0, stream>>>(loadedmask, WPR);

    int waves = B + C;
    int threads_needed = waves * 64;
    norms_scatter<<<(threads_needed + 255) / 256, 256, 0, stream>>>(
        V, T, ids, loadedmask, inv_v, inv_t, B, C, n_loaded);

    dim3 cgrid((WPR + 3) / 4, B);
    compress_labels<<<cgrid, 256, 0, stream>>>(label, loadedmask, posmask, C, WPR);

    count_pos<<<(B + 3) / 4, 256, 0, stream>>>(posmask, nposf, B, WPR);

    dim3 grid(NB, B / TM);
    gemm_mfma<<<grid, 256, 0, stream>>>(V, T, posmask, loadedmask, inv_v, inv_t,
                                        denomP, posP, C, WPR);

    finalize<<<1, 512, 0, stream>>>(denomP, posP, nposf, (float*)d_out, B, NB);
}

// Round 5
// 316.381 us; speedup vs baseline: 2.8326x; 1.3054x over previous
//
#include <hip/hip_runtime.h>
#include <math.h>

// Problem constants: B=512, C=50000, D=256.
#define D_DIM 256
#define TM 128
#define TN 128
#define LSTR 40   // LDS row stride in bf16 elems (80 B, breaks bank pattern)

typedef __attribute__((ext_vector_type(8))) short short8;
typedef __attribute__((ext_vector_type(4))) float floatx4;
typedef unsigned long long u64;

__device__ __forceinline__ unsigned short f2bf(float f) {
    unsigned int u = __float_as_uint(f);
    u += 0x7FFFu + ((u >> 16) & 1u);   // round-to-nearest-even
    return (unsigned short)(u >> 16);
}

__device__ __forceinline__ short8 pack8(float4 x, float4 y, float s) {
    short8 r;
    r[0] = (short)f2bf(x.x * s); r[1] = (short)f2bf(x.y * s);
    r[2] = (short)f2bf(x.z * s); r[3] = (short)f2bf(x.w * s);
    r[4] = (short)f2bf(y.x * s); r[5] = (short)f2bf(y.y * s);
    r[6] = (short)f2bf(y.z * s); r[7] = (short)f2bf(y.w * s);
    return r;
}

// ---------------- init: zero loadedmask only ----------------
__global__ void init_zero(u64* lm, int nwords) {
    int i = blockIdx.x * blockDim.x + threadIdx.x;
    if (i < nwords) lm[i] = 0ull;
}

// ---------------- row norms (one wave per row) + build loadedmask via int atomicOr ----
__global__ void norms_scatter(const float* __restrict__ V, const float* __restrict__ T,
                              const int* __restrict__ ids, u64* __restrict__ loadedmask,
                              float* __restrict__ inv_v, float* __restrict__ inv_t,
                              int B, int C, int n_loaded) {
    int gtid = blockIdx.x * blockDim.x + threadIdx.x;
    if (gtid < n_loaded) {
        int id = ids[gtid];
        atomicOr(&loadedmask[id >> 6], 1ull << (id & 63));   // native int64 atomic
    }

    int wave = gtid >> 6;
    int lane = threadIdx.x & 63;
    if (wave >= B + C) return;  // whole wave uniform
    const float* src = (wave < B) ? (V + (size_t)wave * D_DIM)
                                  : (T + (size_t)(wave - B) * D_DIM);
    float4 x = ((const float4*)src)[lane];
    float ss = x.x * x.x + x.y * x.y + x.z * x.z + x.w * x.w;
    #pragma unroll
    for (int off = 32; off > 0; off >>= 1) ss += __shfl_xor(ss, off);
    if (lane == 0) {
        float nrm = sqrtf(ss);
        if (wave < B) inv_v[wave] = 1.0f / nrm;                 // visual: no eps
        else          inv_t[wave - B] = 1.0f / (1e-6f + nrm);   // text: +1e-6 on norm
    }
}

// ---------------- compress labels -> per-row 64-bit posmask words (no atomics) -------
// One wave covers 256 consecutive cols of one row: 4 independent loads -> 4 ballots.
__global__ void compress_labels(const int* __restrict__ label,
                                const u64* __restrict__ loadedmask,
                                u64* __restrict__ posmask,
                                int C, int WPR) {
    int row  = blockIdx.y;
    int wir  = blockIdx.x * 4 + (threadIdx.x >> 6);   // wave index within row
    int lane = threadIdx.x & 63;
    int base = wir << 8;                              // 256 cols per wave
    if (base >= C) return;
    const int* lp = label + (size_t)row * C;

    int lab[4];
    #pragma unroll
    for (int j = 0; j < 4; j++) {
        int col = base + (j << 6) + lane;
        lab[j] = (col < C) ? lp[col] : 0;             // 4 independent coalesced loads
    }
    #pragma unroll
    for (int j = 0; j < 4; j++) {
        int wcol = (base >> 6) + j;
        if (wcol < WPR) {
            u64 ldw  = loadedmask[wcol];
            u64 posw = __ballot(lab[j] && ((ldw >> lane) & 1));
            if (lane == 0) posmask[(size_t)row * WPR + wcol] = posw;
        }
    }
}

// ---------------- bf16 MFMA GEMM (S = Vn * Tn^T) + fused masked epilogue -------------
// Writes per-block partials (no global atomics).
__global__ __launch_bounds__(256) void gemm_mfma(
    const float* __restrict__ V, const float* __restrict__ T,
    const u64* __restrict__ posmask, const u64* __restrict__ loadedmask,
    const float* __restrict__ inv_v, const float* __restrict__ inv_t,
    float* __restrict__ denomP, float* __restrict__ posP,
    int C, int WPR) {
    __shared__ unsigned short As[TM * LSTR];   // [row][k] bf16, stride 40
    __shared__ unsigned short Bs[TN * LSTR];
    __shared__ float sDen[TM], sPos[TM];

    const int tid  = threadIdx.x;
    const int lane = tid & 63;
    const int w    = tid >> 6;
    const int m0 = blockIdx.y * TM;
    const int n0 = blockIdx.x * TN;

    if (tid < TM) { sDen[tid] = 0.f; sPos[tid] = 0.f; }

    // ---- staging: wave w stages tile rows [w*32, w*32+32) of A and B
    const int sr = lane >> 2;          // 0..15 row within issue
    const int kq = lane & 3;           // k-chunk 0..3 (8 floats each)
    const int kb = kq * 8;
    const int ra0 = w * 32 + sr;       // issue-0 tile row; issue-1 = +16
    const int gm0 = m0 + ra0, gm1 = gm0 + 16;
    const float sa0 = inv_v[gm0], sa1 = inv_v[gm1];
    int gc0 = n0 + ra0, gc1 = gc0 + 16;
    const float sb0 = (gc0 < C) ? inv_t[gc0] : 0.f;
    const float sb1 = (gc1 < C) ? inv_t[gc1] : 0.f;
    if (gc0 >= C) gc0 = 0;
    if (gc1 >= C) gc1 = 0;
    const float* pa0 = V + (size_t)gm0 * D_DIM + kb;
    const float* pa1 = V + (size_t)gm1 * D_DIM + kb;
    const float* pb0 = T + (size_t)gc0 * D_DIM + kb;
    const float* pb1 = T + (size_t)gc1 * D_DIM + kb;
    unsigned short* wa0 = &As[ra0 * LSTR + kb];
    unsigned short* wa1 = &As[(ra0 + 16) * LSTR + kb];
    unsigned short* wb0 = &Bs[ra0 * LSTR + kb];
    unsigned short* wb1 = &Bs[(ra0 + 16) * LSTR + kb];

    // ---- compute-side: 2x2 waves, each 64x64 via 4x4 fragments of 16x16x32
    const int wm = (w >> 1) * 64;
    const int wn = (w & 1) * 64;
    const int fr = lane & 15;
    const int quad = lane >> 4;

    floatx4 acc[4][4];
    #pragma unroll
    for (int mi = 0; mi < 4; mi++)
        #pragma unroll
        for (int ni = 0; ni < 4; ni++) acc[mi][ni] = (floatx4)0.f;

    float4 a00 = *(const float4*)(pa0 + 0), a01 = *(const float4*)(pa0 + 4);
    float4 a10 = *(const float4*)(pa1 + 0), a11 = *(const float4*)(pa1 + 4);
    float4 b00 = *(const float4*)(pb0 + 0), b01 = *(const float4*)(pb0 + 4);
    float4 b10 = *(const float4*)(pb1 + 0), b11 = *(const float4*)(pb1 + 4);

    #pragma unroll
    for (int kt = 0; kt < D_DIM / 32; ++kt) {
        if (kt) __syncthreads();  // protect previous iter's frag reads
        *(short8*)wa0 = pack8(a00, a01, sa0);
        *(short8*)wa1 = pack8(a10, a11, sa1);
        *(short8*)wb0 = pack8(b00, b01, sb0);
        *(short8*)wb1 = pack8(b10, b11, sb1);
        if (kt + 1 < D_DIM / 32) {
            int ko = (kt + 1) * 32;
            a00 = *(const float4*)(pa0 + ko); a01 = *(const float4*)(pa0 + ko + 4);
            a10 = *(const float4*)(pa1 + ko); a11 = *(const float4*)(pa1 + ko + 4);
            b00 = *(const float4*)(pb0 + ko); b01 = *(const float4*)(pb0 + ko + 4);
            b10 = *(const float4*)(pb1 + ko); b11 = *(const float4*)(pb1 + ko + 4);
        }
        __syncthreads();
        short8 af[4], bf[4];
        #pragma unroll
        for (int mi = 0; mi < 4; mi++)
            af[mi] = *(const short8*)&As[(wm + mi * 16 + fr) * LSTR + quad * 8];
        #pragma unroll
        for (int ni = 0; ni < 4; ni++)
            bf[ni] = *(const short8*)&Bs[(wn + ni * 16 + fr) * LSTR + quad * 8];
        #pragma unroll
        for (int mi = 0; mi < 4; mi++)
            #pragma unroll
            for (int ni = 0; ni < 4; ni++)
                acc[mi][ni] = __builtin_amdgcn_mfma_f32_16x16x32_bf16(
                    af[mi], bf[ni], acc[mi][ni], 0, 0, 0);
    }

    // ---- epilogue: mask-word based per-row reduction.
    // D layout: row = quad*4 + reg, col = lane&15 (within each 16x16 fragment).
    const int wcol = (n0 + wn) >> 6;
    const u64 loadedw = loadedmask[wcol];
    #pragma unroll
    for (int mi = 0; mi < 4; mi++) {
        #pragma unroll
        for (int i = 0; i < 4; i++) {
            const int mloc = wm + mi * 16 + quad * 4 + i;
            const int gr = m0 + mloc;
            const u64 posw = posmask[(size_t)gr * WPR + wcol];
            const u64 negw = loadedw & ~posw;
            float den = 0.f, pos = 0.f;
            #pragma unroll
            for (int ni = 0; ni < 4; ni++) {
                const float s = acc[mi][ni][i];
                const int b = ni * 16 + fr;
                if ((negw >> b) & 1) den += __expf(s);
                if ((posw >> b) & 1) pos += s;
            }
            // reduce across the 16 lanes of this quad (same output row)
            #pragma unroll
            for (int off = 8; off >= 1; off >>= 1) {
                den += __shfl_xor(den, off);
                pos += __shfl_xor(pos, off);
            }
            if (fr == 0) {   // LDS atomics only (fast, block-local)
                if (den != 0.f) atomicAdd(&sDen[mloc], den);
                if (pos != 0.f) atomicAdd(&sPos[mloc], pos);
            }
        }
    }
    __syncthreads();
    if (tid < TM) {
        // partial index: [bn][global row], coalesced 128-float store
        size_t idx = (size_t)blockIdx.x * (gridDim.y * TM) + m0 + tid;
        denomP[idx] = sDen[tid];
        posP[idx]   = sPos[tid];
    }
}

// ---------------- reduce_rows: one wave per row; sums partials + popcounts masks -----
__global__ void reduce_rows(const float* __restrict__ denomP, const float* __restrict__ posP,
                            const u64* __restrict__ posmask, float* __restrict__ pr,
                            int B, int NB, int WPR) {
    int row  = blockIdx.x * 4 + (threadIdx.x >> 6);
    int lane = threadIdx.x & 63;
    if (row >= B) return;
    float den = 0.f, pos = 0.f;
    for (int bn = lane; bn < NB; bn += 64) {
        den += denomP[(size_t)bn * B + row];
        pos += posP[(size_t)bn * B + row];
    }
    int cnt = 0;
    for (int j = lane; j < WPR; j += 64)
        cnt += __popcll(posmask[(size_t)row * WPR + j]);
    #pragma unroll
    for (int off = 32; off > 0; off >>= 1) {
        den += __shfl_xor(den, off);
        pos += __shfl_xor(pos, off);
        cnt += __shfl_xor(cnt, off);
    }
    if (lane == 0) pr[row] = logf(den) - pos / (float)cnt;
}

// ---------------- final mean over B rows ----------------
__global__ void final_mean(const float* __restrict__ pr, float* __restrict__ out, int B) {
    __shared__ float red[512];
    int tid = threadIdx.x;
    red[tid] = (tid < B) ? pr[tid] : 0.f;
    __syncthreads();
    for (int s = 256; s > 0; s >>= 1) {
        if (tid < s) red[tid] += red[tid + s];
        __syncthreads();
    }
    if (tid == 0) out[0] = red[0] / (float)B;
}

extern "C" void kernel_launch(void* const* d_in, const int* in_sizes, int n_in,
                              void* d_out, int out_size, void* d_ws, size_t ws_size,
                              hipStream_t stream) {
    const float* V     = (const float*)d_in[0];
    const float* T     = (const float*)d_in[1];
    const int*   label = (const int*)d_in[2];
    const int*   ids   = (const int*)d_in[3];
    int B = in_sizes[0] / D_DIM;   // 512
    int C = in_sizes[1] / D_DIM;   // 50000
    int n_loaded = in_sizes[3];    // 40000
    int WPR = (C + 63) >> 6;       // mask words per row (782)
    int NB  = (C + TN - 1) / TN;   // n-blocks (391)

    // ws layout (bytes):
    //   0        : pr    [512 f]
    //   2048     : inv_v [512 f]
    //   4096     : inv_t [C f]               (ends 204096)
    //   204096   : loadedmask [WPR u64]      (6256 B; 8-aligned)
    //   210432   : posmask [B*WPR u64]       (3.20 MB, ends 3413504)
    //   3413504  : denomP [NB*B f]           (800768 B, ends 4214272)
    //   4214272  : posP   [NB*B f]           (800768 B, ends 5015040)
    char* ws = (char*)d_ws;
    float* pr      = (float*)(ws + 0);
    float* inv_v   = (float*)(ws + 2048);
    float* inv_t   = (float*)(ws + 4096);
    u64*   loadedmask = (u64*)(ws + 204096);
    u64*   posmask    = (u64*)(ws + 210432);
    float* denomP  = (float*)(ws + 3413504);
    float* posP    = (float*)(ws + 4214272);

    init_zero<<<(WPR + 255) / 256, 256, 0, stream>>>(loadedmask, WPR);

    int waves = B + C;
    int threads_needed = waves * 64;
    norms_scatter<<<(threads_needed + 255) / 256, 256, 0, stream>>>(
        V, T, ids, loadedmask, inv_v, inv_t, B, C, n_loaded);

    int wavesPerRow = (C + 255) / 256;                 // 196
    dim3 cgrid((wavesPerRow + 3) / 4, B);
    compress_labels<<<cgrid, 256, 0, stream>>>(label, loadedmask, posmask, C, WPR);

    dim3 grid(NB, B / TM);
    gemm_mfma<<<grid, 256, 0, stream>>>(V, T, posmask, loadedmask, inv_v, inv_t,
                                        denomP, posP, C, WPR);

    reduce_rows<<<(B + 3) / 4, 256, 0, stream>>>(denomP, posP, posmask, pr, B, NB, WPR);

    final_mean<<<1, 512, 0, stream>>>(pr, (float*)d_out, B);
}

// Round 6
// 264.905 us; speedup vs baseline: 3.3830x; 1.1943x over previous
//
#include <hip/hip_runtime.h>
#include <math.h>

// Problem constants: B=512, C=50000, D=256.
#define D_DIM 256
#define TM 128
#define TN 128
#define BK 32    // K-tile depth (bf16 elems); 8 K-iterations

typedef __attribute__((ext_vector_type(8))) short short8;
typedef __attribute__((ext_vector_type(4))) float floatx4;
typedef unsigned long long u64;

__device__ __forceinline__ unsigned short f2bf(float f) {
    unsigned int u = __float_as_uint(f);
    u += 0x7FFFu + ((u >> 16) & 1u);   // round-to-nearest-even
    return (unsigned short)(u >> 16);
}

// async global->LDS 16B: deposits lane l's 16B at ldsbase + l*16 (wave-uniform base)
__device__ __forceinline__ void gload16(const void* g, void* lds) {
    __builtin_amdgcn_global_load_lds(
        (const __attribute__((address_space(1))) unsigned int*)g,
        (__attribute__((address_space(3))) unsigned int*)lds, 16, 0, 0);
}

// ---------------- init: zero loadedmask ----------------
__global__ void init_zero(u64* lm, int nwords) {
    int i = blockIdx.x * blockDim.x + threadIdx.x;
    if (i < nwords) lm[i] = 0ull;
}

// ---- prep: row norms + normalized bf16 conversion + loadedmask scatter --------------
// One wave per row. Butterfly leaves the full sum in every lane; each lane then
// converts its own float4 -> ushort4 (8B coalesced store).
__global__ void prep(const float* __restrict__ V, const float* __restrict__ T,
                     const int* __restrict__ ids, u64* __restrict__ loadedmask,
                     unsigned short* __restrict__ Vb, unsigned short* __restrict__ Tb,
                     int B, int C, int n_loaded) {
    int gtid = blockIdx.x * blockDim.x + threadIdx.x;
    if (gtid < n_loaded) {
        int id = ids[gtid];
        atomicOr(&loadedmask[id >> 6], 1ull << (id & 63));   // native int64 atomic
    }
    int wave = gtid >> 6;
    int lane = threadIdx.x & 63;
    if (wave >= B + C) return;  // whole wave uniform
    bool isV = wave < B;
    const float* src = isV ? (V + (size_t)wave * D_DIM)
                           : (T + (size_t)(wave - B) * D_DIM);
    float4 x = ((const float4*)src)[lane];
    float ss = x.x * x.x + x.y * x.y + x.z * x.z + x.w * x.w;
    #pragma unroll
    for (int off = 32; off > 0; off >>= 1) ss += __shfl_xor(ss, off);
    float nrm = sqrtf(ss);
    float s = isV ? (1.0f / nrm) : (1.0f / (1e-6f + nrm));   // eps on text norms only
    ushort4 o;
    o.x = f2bf(x.x * s); o.y = f2bf(x.y * s);
    o.z = f2bf(x.z * s); o.w = f2bf(x.w * s);
    unsigned short* dst = isV ? (Vb + (size_t)wave * D_DIM)
                              : (Tb + (size_t)(wave - B) * D_DIM);
    ((ushort4*)dst)[lane] = o;
}

// ---- fused gemm: bf16 MFMA S-tile + in-block label bitmap + masked reduction --------
// grid = (B/TM = 4, NB = 391); m-block fastest so 4 blocks share one T-tile (L2 reuse).
__global__ __launch_bounds__(256) void gemm_fused(
    const unsigned short* __restrict__ Vb, const unsigned short* __restrict__ Tb,
    const int* __restrict__ label, const u64* __restrict__ loadedmask,
    float* __restrict__ denomP, float* __restrict__ posP, float* __restrict__ npP,
    int C) {
    __shared__ unsigned short As[TM * BK];   // 8 KB, [row][k], stride 32 (global_load_lds layout)
    __shared__ unsigned short Bs[TN * BK];   // 8 KB
    __shared__ unsigned char  Lab[TM * TN];  // 16 KB: label!=0 bytes for this S-tile
    __shared__ float sDen[TM], sPos[TM], sNp[TM];

    const int tid  = threadIdx.x;
    const int lane = tid & 63;
    const int w    = tid >> 6;
    const int m0 = blockIdx.x * TM;
    const int n0 = blockIdx.y * TN;

    if (tid < TM) { sDen[tid] = 0.f; sPos[tid] = 0.f; sNp[tid] = 0.f; }

    // ---- stage this block's 128x128 label patch into LDS bytes (consumed in epilogue;
    // loads issue now, latency hidden under the K-loop's MFMA work).
    if (n0 + TN <= C) {
        #pragma unroll
        for (int j = 0; j < 16; ++j) {
            int idx = j * 256 + tid;          // 0..4095
            int r  = idx >> 5;                // 32 int4 per 128-col row
            int c4 = idx & 31;
            int4 v = *(const int4*)(label + (size_t)(m0 + r) * C + n0 + c4 * 4);
            unsigned int p = (v.x ? 1u : 0u) | (v.y ? 0x100u : 0u) |
                             (v.z ? 0x10000u : 0u) | (v.w ? 0x1000000u : 0u);
            *(unsigned int*)&Lab[r * TN + c4 * 4] = p;
        }
    } else {   // last n-block only: guarded scalar loads
        for (int j = 0; j < 16; ++j) {
            int idx = j * 256 + tid;
            int r  = idx >> 5;
            int c4 = idx & 31;
            const int* lp = label + (size_t)(m0 + r) * C;
            unsigned int p = 0;
            #pragma unroll
            for (int e = 0; e < 4; ++e) {
                int c = n0 + c4 * 4 + e;
                if (c < C && lp[c]) p |= 1u << (8 * e);
            }
            *(unsigned int*)&Lab[r * TN + c4 * 4] = p;
        }
    }

    // ---- async-staging addresses: wave w covers tile rows [w*32, w*32+32)
    const int sra = lane >> 2;          // 0..15: row within 16-row group
    const int kc  = (lane & 3) * 8;     // 8-elem (16B) k-chunk
    int ga = m0 + w * 32 + sra;
    int gb0 = n0 + w * 32 + sra;
    int gb1 = gb0 + 16;
    if (gb0 >= C) gb0 = C - 1;          // OOB rows: valid address, masked later
    if (gb1 >= C) gb1 = C - 1;
    const unsigned short* gA0 = Vb + (size_t)ga * D_DIM + kc;
    const unsigned short* gA1 = gA0 + (size_t)16 * D_DIM;
    const unsigned short* gB0 = Tb + (size_t)gb0 * D_DIM + kc;
    const unsigned short* gB1 = Tb + (size_t)gb1 * D_DIM + kc;
    unsigned short* lA0 = &As[w * 32 * BK];          // wave-uniform LDS bases
    unsigned short* lA1 = lA0 + 16 * BK;
    unsigned short* lB0 = &Bs[w * 32 * BK];
    unsigned short* lB1 = lB0 + 16 * BK;

    // ---- compute mapping: 2x2 waves, each 64x64 via 4x4 frags of 16x16x32
    const int wm = (w >> 1) * 64;
    const int wn = (w & 1) * 64;
    const int fr = lane & 15;
    const int quad = lane >> 4;

    floatx4 acc[4][4];
    #pragma unroll
    for (int mi = 0; mi < 4; mi++)
        #pragma unroll
        for (int ni = 0; ni < 4; ni++) acc[mi][ni] = (floatx4)0.f;

    #pragma unroll
    for (int kt = 0; kt < D_DIM / BK; ++kt) {
        if (kt) __syncthreads();        // all waves done reading previous tile
        const int kb = kt * BK;
        gload16(gA0 + kb, lA0);
        gload16(gA1 + kb, lA1);
        gload16(gB0 + kb, lB0);
        gload16(gB1 + kb, lB1);
        __syncthreads();                // drains vmcnt before barrier
        short8 af[4], bf[4];
        #pragma unroll
        for (int mi = 0; mi < 4; mi++)
            af[mi] = *(const short8*)&As[(wm + mi * 16 + fr) * BK + quad * 8];
        #pragma unroll
        for (int ni = 0; ni < 4; ni++)
            bf[ni] = *(const short8*)&Bs[(wn + ni * 16 + fr) * BK + quad * 8];
        #pragma unroll
        for (int mi = 0; mi < 4; mi++)
            #pragma unroll
            for (int ni = 0; ni < 4; ni++)
                acc[mi][ni] = __builtin_amdgcn_mfma_f32_16x16x32_bf16(
                    af[mi], bf[ni], acc[mi][ni], 0, 0, 0);
    }

    // ---- epilogue: D layout row = quad*4 + reg, col = lane&15 per 16x16 frag.
    const u64 loadedw = loadedmask[(n0 + wn) >> 6];   // this wave's 64-col window
    #pragma unroll
    for (int mi = 0; mi < 4; mi++) {
        #pragma unroll
        for (int i = 0; i < 4; i++) {
            const int mloc = wm + mi * 16 + quad * 4 + i;
            float den = 0.f, pos = 0.f, np = 0.f;
            #pragma unroll
            for (int ni = 0; ni < 4; ni++) {
                const int nloc = wn + ni * 16 + fr;
                const int bit  = ni * 16 + fr;
                const float s = acc[mi][ni][i];
                const int lab = Lab[mloc * TN + nloc];
                if ((loadedw >> bit) & 1) {
                    if (lab) { pos += s; np += 1.f; }
                    else     { den += __expf(s); }
                }
            }
            #pragma unroll
            for (int off = 8; off >= 1; off >>= 1) {   // reduce the 16-lane quad row
                den += __shfl_xor(den, off);
                pos += __shfl_xor(pos, off);
                np  += __shfl_xor(np, off);
            }
            if (fr == 0) {
                if (den != 0.f) atomicAdd(&sDen[mloc], den);
                if (np  != 0.f) { atomicAdd(&sPos[mloc], pos); atomicAdd(&sNp[mloc], np); }
            }
        }
    }
    __syncthreads();
    if (tid < TM) {   // per-block partials: [n-block][global row], coalesced
        size_t idx = (size_t)blockIdx.y * 512 + m0 + tid;
        denomP[idx] = sDen[tid];
        posP[idx]   = sPos[tid];
        npP[idx]    = sNp[tid];
    }
}

// ---- reduce_rows: one wave per row sums the 391 partials ----------------------------
__global__ void reduce_rows(const float* __restrict__ denomP, const float* __restrict__ posP,
                            const float* __restrict__ npP, float* __restrict__ pr,
                            int B, int NB) {
    int row  = blockIdx.x * 4 + (threadIdx.x >> 6);
    int lane = threadIdx.x & 63;
    if (row >= B) return;
    float den = 0.f, pos = 0.f, np = 0.f;
    for (int bn = lane; bn < NB; bn += 64) {
        den += denomP[(size_t)bn * B + row];
        pos += posP[(size_t)bn * B + row];
        np  += npP[(size_t)bn * B + row];
    }
    #pragma unroll
    for (int off = 32; off > 0; off >>= 1) {
        den += __shfl_xor(den, off);
        pos += __shfl_xor(pos, off);
        np  += __shfl_xor(np, off);
    }
    if (lane == 0) pr[row] = logf(den) - pos / np;
}

// ---- final mean over B rows ----------------
__global__ void final_mean(const float* __restrict__ pr, float* __restrict__ out, int B) {
    __shared__ float red[512];
    int tid = threadIdx.x;
    red[tid] = (tid < B) ? pr[tid] : 0.f;
    __syncthreads();
    for (int s = 256; s > 0; s >>= 1) {
        if (tid < s) red[tid] += red[tid + s];
        __syncthreads();
    }
    if (tid == 0) out[0] = red[0] / (float)B;
}

extern "C" void kernel_launch(void* const* d_in, const int* in_sizes, int n_in,
                              void* d_out, int out_size, void* d_ws, size_t ws_size,
                              hipStream_t stream) {
    const float* V     = (const float*)d_in[0];
    const float* T     = (const float*)d_in[1];
    const int*   label = (const int*)d_in[2];
    const int*   ids   = (const int*)d_in[3];
    int B = in_sizes[0] / D_DIM;   // 512
    int C = in_sizes[1] / D_DIM;   // 50000
    int n_loaded = in_sizes[3];    // 40000
    int WPR = (C + 63) >> 6;       // loadedmask words (782)
    int NB  = (C + TN - 1) / TN;   // n-blocks (391)

    // ws layout (bytes):
    //   0        : pr [512 f]                       (2048)
    //   2048     : loadedmask [782 u64]             (ends 8304, pad to 8320)
    //   8320     : Vb [512*256 bf16]                (262144 -> ends 270464)
    //   270464   : Tb [50000*256 bf16]              (25.6 MB -> ends 25870464)
    //   25870464 : denomP [NB*512 f]                (ends 26671232)
    //   26671232 : posP                             (ends 27472000)
    //   27472000 : npP                              (ends 28272768)
    char* ws = (char*)d_ws;
    float* pr      = (float*)(ws + 0);
    u64*   loadedmask = (u64*)(ws + 2048);
    unsigned short* Vb = (unsigned short*)(ws + 8320);
    unsigned short* Tb = (unsigned short*)(ws + 270464);
    float* denomP  = (float*)(ws + 25870464);
    float* posP    = (float*)(ws + 26671232);
    float* npP     = (float*)(ws + 27472000);

    init_zero<<<(WPR + 255) / 256, 256, 0, stream>>>(loadedmask, WPR);

    int threads_needed = (B + C) * 64;
    prep<<<(threads_needed + 255) / 256, 256, 0, stream>>>(
        V, T, ids, loadedmask, Vb, Tb, B, C, n_loaded);

    dim3 grid(B / TM, NB);   // m-block fastest: 4 blocks share one T-tile
    gemm_fused<<<grid, 256, 0, stream>>>(Vb, Tb, label, loadedmask,
                                         denomP, posP, npP, C);

    reduce_rows<<<(B + 3) / 4, 256, 0, stream>>>(denomP, posP, npP, pr, B, NB);

    final_mean<<<1, 512, 0, stream>>>(pr, (float*)d_out, B);
}